// Round 1
// baseline (419.201 us; speedup 1.0000x reference)
//
#include <hip/hip_runtime.h>
#include <math.h>

#define TOKENS 8192
#define DIM 4096
#define NEXP 256
#define TK 8
#define NGRP 8
#define TKGRP 4
#define ROUTE_SCALE 2.5f

// ---------------------------------------------------------------------------
// Kernel 1: scores[t][e] = sigmoid(dot(x[t,:], W[e,:]))
// fp32 VALU GEMM: BM=64 tokens, BN=64 experts, BK=32, 256 threads, 4x4/thread.
// Both x and W are K-contiguous (A * B^T shape) -> coalesced float4 loads.
// ---------------------------------------------------------------------------
__global__ __launch_bounds__(256) void score_gemm(const float* __restrict__ x,
                                                  const float* __restrict__ W,
                                                  float* __restrict__ scores) {
    // [k][m] layout, stride 68 floats (272 B, 16B-aligned rows, breaks pow2 banks)
    __shared__ __align__(16) float As[32][68];
    __shared__ __align__(16) float Bs[32][68];

    const int t0 = blockIdx.x << 6;
    const int e0 = blockIdx.y << 6;
    const int tid = threadIdx.x;
    const int tx = tid & 15;   // expert sub-tile
    const int ty = tid >> 4;   // token sub-tile
    const int lr = tid >> 3;          // 0..31  (row within 64-row tile, +32 for second)
    const int lc = (tid & 7) << 2;    // 0..28  (k offset, float4)

    float acc[4][4];
#pragma unroll
    for (int i = 0; i < 4; i++)
#pragma unroll
        for (int j = 0; j < 4; j++) acc[i][j] = 0.0f;

    const float* xA = x + (size_t)(t0 + lr) * DIM + lc;
    const float* xB = x + (size_t)(t0 + lr + 32) * DIM + lc;
    const float* wA = W + (size_t)(e0 + lr) * DIM + lc;
    const float* wB = W + (size_t)(e0 + lr + 32) * DIM + lc;

    for (int kk = 0; kk < DIM; kk += 32) {
        float4 a0 = *(const float4*)(xA + kk);
        float4 a1 = *(const float4*)(xB + kk);
        float4 b0 = *(const float4*)(wA + kk);
        float4 b1 = *(const float4*)(wB + kk);
        __syncthreads();   // previous tile's compute done before overwrite
        As[lc + 0][lr] = a0.x; As[lc + 1][lr] = a0.y;
        As[lc + 2][lr] = a0.z; As[lc + 3][lr] = a0.w;
        As[lc + 0][lr + 32] = a1.x; As[lc + 1][lr + 32] = a1.y;
        As[lc + 2][lr + 32] = a1.z; As[lc + 3][lr + 32] = a1.w;
        Bs[lc + 0][lr] = b0.x; Bs[lc + 1][lr] = b0.y;
        Bs[lc + 2][lr] = b0.z; Bs[lc + 3][lr] = b0.w;
        Bs[lc + 0][lr + 32] = b1.x; Bs[lc + 1][lr + 32] = b1.y;
        Bs[lc + 2][lr + 32] = b1.z; Bs[lc + 3][lr + 32] = b1.w;
        __syncthreads();
#pragma unroll
        for (int k = 0; k < 32; k++) {
            float4 av = *(const float4*)&As[k][ty << 2];
            float4 bv = *(const float4*)&Bs[k][tx << 2];
            float a_[4] = {av.x, av.y, av.z, av.w};
            float b_[4] = {bv.x, bv.y, bv.z, bv.w};
#pragma unroll
            for (int i = 0; i < 4; i++)
#pragma unroll
                for (int j = 0; j < 4; j++)
                    acc[i][j] = fmaf(a_[i], b_[j], acc[i][j]);
        }
    }

#pragma unroll
    for (int i = 0; i < 4; i++) {
        float4 o;
        o.x = 1.0f / (1.0f + expf(-acc[i][0]));
        o.y = 1.0f / (1.0f + expf(-acc[i][1]));
        o.z = 1.0f / (1.0f + expf(-acc[i][2]));
        o.w = 1.0f / (1.0f + expf(-acc[i][3]));
        *(float4*)&scores[(size_t)(t0 + (ty << 2) + i) * NEXP + e0 + (tx << 2)] = o;
    }
}

// ---------------------------------------------------------------------------
// Kernel 2: per-token routing. One wave (64 lanes) per token; lane l owns
// experts 4l..4l+3; group g = experts 32g..32g+31 = lanes 8g..8g+7.
// ---------------------------------------------------------------------------
__global__ __launch_bounds__(64) void route_kernel(const float* __restrict__ scores,
                                                   const float* __restrict__ bias,
                                                   float* __restrict__ out_w,
                                                   float* __restrict__ out_i) {
    const int t = blockIdx.x;
    const int l = threadIdx.x;  // 0..63

    float4 sc4 = *(const float4*)&scores[(size_t)t * NEXP + (l << 2)];
    float4 b4 = *(const float4*)&bias[l << 2];
    float sc[4] = {sc4.x, sc4.y, sc4.z, sc4.w};                    // original sigmoid scores
    float sb[4] = {sc4.x + b4.x, sc4.y + b4.y, sc4.z + b4.z, sc4.w + b4.w};  // biased

    // local top-2 of 4 biased values
    float hi1 = fmaxf(sb[0], sb[1]), lo1 = fminf(sb[0], sb[1]);
    float hi2 = fmaxf(sb[2], sb[3]), lo2 = fminf(sb[2], sb[3]);
    float m1 = fmaxf(hi1, hi2);
    float m2 = fmaxf(fminf(hi1, hi2), fmaxf(lo1, lo2));

    // merge top-2 across the 8 lanes of the group (xor 1,2,4 stays in-group)
#pragma unroll
    for (int m = 1; m < 8; m <<= 1) {
        float o1 = __shfl_xor(m1, m, 64);
        float o2 = __shfl_xor(m2, m, 64);
        float nm1 = fmaxf(m1, o1);
        float nm2 = fmaxf(fminf(m1, o1), fmaxf(m2, o2));
        m1 = nm1; m2 = nm2;
    }
    float gscore = m1 + m2;   // group score (same on all 8 lanes of the group)

    // broadcast all 8 group scores to every lane
    float gs[8];
#pragma unroll
    for (int g = 0; g < 8; g++) gs[g] = __shfl(gscore, g << 3, 64);

    const int mygrp = l >> 3;
    const float mg = gscore;
    int rank = 0;
#pragma unroll
    for (int g = 0; g < 8; g++) {
        bool better = (gs[g] > mg) || (gs[g] == mg && g < mygrp);
        rank += (g != mygrp && better) ? 1 : 0;
    }
    const bool sel = rank < TKGRP;

    float cand[4];
#pragma unroll
    for (int c = 0; c < 4; c++) cand[c] = sel ? sb[c] : 0.0f;

    // serial top-8: wave argmax with lower-index tie-break (matches lax.top_k)
    float w[8];
    float widx[8];
    float wsum = 0.0f;
#pragma unroll
    for (int r = 0; r < 8; r++) {
        float v = cand[0];
        int idx = (l << 2);
#pragma unroll
        for (int c = 1; c < 4; c++) {
            if (cand[c] > v) { v = cand[c]; idx = (l << 2) + c; }
        }
#pragma unroll
        for (int m = 32; m >= 1; m >>= 1) {
            float ov = __shfl_xor(v, m, 64);
            int oi = __shfl_xor(idx, m, 64);
            if (ov > v || (ov == v && oi < idx)) { v = ov; idx = oi; }
        }
        // all lanes agree on (v, idx) now
        const int cc = idx & 3;              // wave-uniform
        const bool own = (idx >> 2) == l;
        cand[0] = (own && cc == 0) ? -__builtin_inff() : cand[0];
        cand[1] = (own && cc == 1) ? -__builtin_inff() : cand[1];
        cand[2] = (own && cc == 2) ? -__builtin_inff() : cand[2];
        cand[3] = (own && cc == 3) ? -__builtin_inff() : cand[3];
        float tmp = (cc == 0) ? sc[0] : (cc == 1) ? sc[1] : (cc == 2) ? sc[2] : sc[3];
        float ws = __shfl(tmp, idx >> 2, 64);   // original (unbiased) score
        w[r] = ws;
        widx[r] = (float)idx;
        wsum += ws;
    }

    const float scale = ROUTE_SCALE / wsum;
    if (l == 0) {
        float* ow = out_w + (size_t)t * TK;
        float* oi = out_i + (size_t)t * TK;
#pragma unroll
        for (int r = 0; r < 8; r++) ow[r] = w[r] * scale;
#pragma unroll
        for (int r = 0; r < 8; r++) oi[r] = widx[r];
    }
}

extern "C" void kernel_launch(void* const* d_in, const int* in_sizes, int n_in,
                              void* d_out, int out_size, void* d_ws, size_t ws_size,
                              hipStream_t stream) {
    const float* x = (const float*)d_in[0];
    const float* W = (const float*)d_in[1];
    const float* bias = (const float*)d_in[2];
    float* out = (float*)d_out;              // [TOKENS*TK weights][TOKENS*TK indices-as-float]
    float* scores = (float*)d_ws;            // 8192*256 f32 = 8 MB scratch

    dim3 gGemm(TOKENS / 64, NEXP / 64);      // 128 x 4 = 512 blocks
    score_gemm<<<gGemm, 256, 0, stream>>>(x, W, scores);

    route_kernel<<<TOKENS, 64, 0, stream>>>(scores, bias, out, out + (size_t)TOKENS * TK);
}